// Round 8
// baseline (308.625 us; speedup 1.0000x reference)
//
#include <hip/hip_runtime.h>

#define H 128
#define W 128
#define C 128
#define NB 4
#define HW (H * W)
#define PXB 32            // pixels per block (quarter row)
#define NSEG (W / PXB)    // 4
#define TPX 64            // pixels per transpose block

// ---------------------------------------------------------------------------
// Pre-pass 1: NCHW -> NHWC transpose of x into workspace (32 MB).
// ---------------------------------------------------------------------------
__global__ __launch_bounds__(256) void transpose_nchw_nhwc(
    const float* __restrict__ x, float* __restrict__ xt) {
  __shared__ float tile[TPX][C + 1];  // 64 x 129 floats = 33 KB
  const int blk = blockIdx.x;
  const int n = blk >> 8;                 // HW/TPX = 256 blocks per image
  const int p0 = (blk & 255) * TPX;
  const float* xn = x + (size_t)n * C * HW;
  float* xtn = xt + (size_t)n * HW * C;

  const int i = threadIdx.x & 63;         // pixel within tile
  const int c0 = threadIdx.x >> 6;        // 0..3
#pragma unroll
  for (int c = c0; c < C; c += 4)
    tile[i][c] = xn[(size_t)c * HW + p0 + i];
  __syncthreads();

  const int cl = threadIdx.x & 31;        // channel quad 0..31
  const int pr = threadIdx.x >> 5;        // 0..7
#pragma unroll
  for (int p = pr; p < TPX; p += 8) {
    float4 v = make_float4(tile[p][4 * cl + 0], tile[p][4 * cl + 1],
                           tile[p][4 * cl + 2], tile[p][4 * cl + 3]);
    *(float4*)(xtn + (size_t)(p0 + p) * C + 4 * cl) = v;
  }
}

// ---------------------------------------------------------------------------
// Pre-pass 2: weight re-layout wg[p][ch][k] -> wt[ch][k][p]  (9216 floats).
// ---------------------------------------------------------------------------
__global__ __launch_bounds__(256) void prep_wt(
    const float* __restrict__ wg, float* __restrict__ wt) {
  const int i = blockIdx.x * 256 + threadIdx.x;  // 36 blocks x 256 = 9216
  const int ch = i / 72;
  const int rem = i % 72;
  const int k = rem >> 3;
  const int p = rem & 7;
  wt[i] = wg[((size_t)p * C + ch) * 9 + k];
}

// ---------------------------------------------------------------------------
// Fused deformable-conv t7 = t3 front-end + dcn_sample back-end.
//  Phases 1/1.5/1.75: t3 verbatim (proven 56-VGPR no-spill conv + tap tables;
//    tap indices premultiplied by C/4).
//  Phase 2: round-6 dcn_sample's proven gather/store: thread (px-pair, quad,
//    kh) computes a 2x2 output block for 4 channels, full-64B-line float4
//    stores, ZERO barriers, no LDS restage (stores never drain at a barrier).
// ---------------------------------------------------------------------------
__global__ __launch_bounds__(256, 4) void dcn_fused_t7(
    const float* __restrict__ xt, const float* __restrict__ wt,
    const float* __restrict__ b, float* __restrict__ out) {

  __shared__ __align__(16) float lsh[4096];  // lacc [16][32][8]
  __shared__ float loff[PXB][9];
  __shared__ int4   ltapi[PXB][4];   // tap pixel indices premultiplied by C/4
  __shared__ float4 ltapw[PXB][4];   // bilinear weights (validity folded in)

  const int t = threadIdx.x;
  const int bxr = blockIdx.x;
  const int bx = ((bxr & 7) << 8) | (bxr >> 3);  // XCD swizzle (2048 = 8*256)
  const int seg = bx & (NSEG - 1);
  const int y = (bx >> 2) & (H - 1);
  const int n = bx >> 9;
  const int x0 = seg * PXB;

  const float* xtn = xt + (size_t)n * HW * C;

  // ---------------- Phase 1: offset conv from NHWC (t3 verbatim) -----------
  {
    const int pp = t & 15;   // pixel pair -> pixels x0+2pp, x0+2pp+1
    const int cg = t >> 4;   // channel group 0..15 (8 channels each)
    const int xb = x0 + 2 * pp;
    const int cb = cg * 8;

    int xs[4];
    float colm[4];
#pragma unroll
    for (int j = 0; j < 4; ++j) {
      int xa = xb - 1 + j;
      colm[j] = ((unsigned)xa < (unsigned)W) ? 1.f : 0.f;
      xs[j] = xa < 0 ? 0 : (xa > W - 1 ? W - 1 : xa);
    }
    int pix[3][4];
    float m[3][4];
#pragma unroll
    for (int r = 0; r < 3; ++r) {
      int yy = y + r - 1;
      float rm = ((unsigned)yy < (unsigned)H) ? 1.f : 0.f;
      int yc = yy < 0 ? 0 : (yy > H - 1 ? H - 1 : yy);
#pragma unroll
      for (int j = 0; j < 4; ++j) {
        m[r][j] = rm * colm[j];
        pix[r][j] = yc * W + xs[j];
      }
    }

    float acc[2][8];
#pragma unroll
    for (int p = 0; p < 8; ++p) { acc[0][p] = 0.f; acc[1][p] = 0.f; }

#pragma unroll
    for (int c2 = 0; c2 < 2; ++c2) {
      float xvq[3][4][4];
#pragma unroll
      for (int r = 0; r < 3; ++r) {
#pragma unroll
        for (int j = 0; j < 4; ++j) {
          float4 v = *(const float4*)(xtn + (size_t)pix[r][j] * C + cb + c2 * 4);
          const float mm = m[r][j];
          xvq[r][j][0] = v.x * mm;
          xvq[r][j][1] = v.y * mm;
          xvq[r][j][2] = v.z * mm;
          xvq[r][j][3] = v.w * mm;
        }
      }
#pragma unroll
      for (int cc = 0; cc < 4; ++cc) {
        const int ch = cb + c2 * 4 + cc;
        const float4* wv4 = (const float4*)(wt + (size_t)ch * 72);
#pragma unroll
        for (int k = 0; k < 9; ++k) {
          const int r = k / 3, kw = k % 3;
          const float4 wa = wv4[2 * k];      // p = 0..3
          const float4 wb = wv4[2 * k + 1];  // p = 4..7
          const float xl = xvq[r][kw][cc];
          const float xr = xvq[r][kw + 1][cc];
          acc[0][0] += xl * wa.x; acc[0][1] += xl * wa.y;
          acc[0][2] += xl * wa.z; acc[0][3] += xl * wa.w;
          acc[0][4] += xl * wb.x; acc[0][5] += xl * wb.y;
          acc[0][6] += xl * wb.z; acc[0][7] += xl * wb.w;
          acc[1][0] += xr * wa.x; acc[1][1] += xr * wa.y;
          acc[1][2] += xr * wa.z; acc[1][3] += xr * wa.w;
          acc[1][4] += xr * wb.x; acc[1][5] += xr * wb.y;
          acc[1][6] += xr * wb.z; acc[1][7] += xr * wb.w;
        }
      }
    }
#pragma unroll
    for (int p = 0; p < 8; ++p) {
      lsh[((size_t)cg * PXB + 2 * pp) * 8 + p] = acc[0][p];
      lsh[((size_t)cg * PXB + 2 * pp + 1) * 8 + p] = acc[1][p];
    }
  }
  __syncthreads();

  // ---------------- Phase 1.5: reduce 16 groups + bias ---------------------
  {
    const int px = t >> 3;  // 0..31
    const int p = t & 7;
    float s = b[p];
#pragma unroll
    for (int g = 0; g < 16; ++g) s += lsh[((size_t)g * PXB + px) * 8 + p];
    loff[px][p] = s;
  }
  __syncthreads();

  // ---------------- Phase 1.75: per (px,pos) tap table ---------------------
  if (t < 128) {
    const int px = t >> 2;
    const int pos = t & 3;
    const int xx = x0 + px;
    float sy = (float)y + loff[px][2 * pos];
    float sx = (float)xx + loff[px][2 * pos + 1];
    float y0f = floorf(sy), x0f = floorf(sx);
    float wy1 = sy - y0f, wx1 = sx - x0f;
    float wy0 = 1.f - wy1, wx0 = 1.f - wx1;
    int iy0 = (int)y0f, ix0 = (int)x0f;
    int iy1 = iy0 + 1, ix1 = ix0 + 1;
    float vy0 = ((unsigned)iy0 < (unsigned)H) ? 1.f : 0.f;
    float vy1 = ((unsigned)iy1 < (unsigned)H) ? 1.f : 0.f;
    float vx0 = ((unsigned)ix0 < (unsigned)W) ? 1.f : 0.f;
    float vx1 = ((unsigned)ix1 < (unsigned)W) ? 1.f : 0.f;
    int cy0 = iy0 < 0 ? 0 : (iy0 > H - 1 ? H - 1 : iy0);
    int cy1 = iy1 < 0 ? 0 : (iy1 > H - 1 ? H - 1 : iy1);
    int cx0 = ix0 < 0 ? 0 : (ix0 > W - 1 ? W - 1 : ix0);
    int cx1 = ix1 < 0 ? 0 : (ix1 > W - 1 ? W - 1 : ix1);
    ltapi[px][pos] = make_int4((cy0 * W + cx0) * (C / 4), (cy0 * W + cx1) * (C / 4),
                               (cy1 * W + cx0) * (C / 4), (cy1 * W + cx1) * (C / 4));
    ltapw[px][pos] = make_float4(wy0 * wx0 * vy0 * vx0, wy0 * wx1 * vy0 * vx1,
                                 wy1 * wx0 * vy1 * vx0, wy1 * wx1 * vy1 * vx1);
  }
  __syncthreads();

  // ---------------- Phase 2: dcn_sample gather + direct full-line stores ---
  {
    const int pair = t & 3;
    const int q = (t >> 2) & 31;   // channel quad
    const int half = t >> 7;       // kh
    const float4* xt4 = (const float4*)xtn;
    float* outn = out + (size_t)n * C * 4 * HW;

#pragma unroll 1
    for (int pass = 0; pass < 4; ++pass) {
      const int px0p = pass * 8 + 2 * pair;
      float sc[2][2][4];
#pragma unroll
      for (int bb = 0; bb < 2; ++bb) {
#pragma unroll
        for (int pp2 = 0; pp2 < 2; ++pp2) {
          const int pos = 2 * half + pp2;
          const int4 o = ltapi[px0p + bb][pos];
          const float4 wv = ltapw[px0p + bb][pos];
          const float4 v00 = xt4[(size_t)o.x + q];
          const float4 v01 = xt4[(size_t)o.y + q];
          const float4 v10 = xt4[(size_t)o.z + q];
          const float4 v11 = xt4[(size_t)o.w + q];
          sc[bb][pp2][0] = wv.x * v00.x + wv.y * v01.x + wv.z * v10.x + wv.w * v11.x;
          sc[bb][pp2][1] = wv.x * v00.y + wv.y * v01.y + wv.z * v10.y + wv.w * v11.y;
          sc[bb][pp2][2] = wv.x * v00.z + wv.y * v01.z + wv.z * v10.z + wv.w * v11.z;
          sc[bb][pp2][3] = wv.x * v00.w + wv.y * v01.w + wv.z * v10.w + wv.w * v11.w;
        }
      }
      float* obase = outn + (size_t)(2 * y + half) * (2 * W) + 2 * (x0 + px0p);
#pragma unroll
      for (int j = 0; j < 4; ++j) {
        *(float4*)(obase + (size_t)(4 * q + j) * (4 * HW)) =
            make_float4(sc[0][0][j], sc[0][1][j], sc[1][0][j], sc[1][1][j]);
      }
    }
  }
}

// ---------------------------------------------------------------------------
// Fallback: original NCHW-gather kernel (used only if workspace too small).
// ---------------------------------------------------------------------------
__global__ __launch_bounds__(256) void dcn_fused(
    const float* __restrict__ x, const float* __restrict__ wg,
    const float* __restrict__ b, float* __restrict__ out) {

  __shared__ float lacc[16][PXB][8];
  __shared__ float loff[PXB][9];

  const int t = threadIdx.x;
  const int bx = blockIdx.x;
  const int seg = bx & (NSEG - 1);
  const int y = (bx >> 2) & (H - 1);
  const int n = bx >> 9;
  const int x0 = seg * PXB;

  const float* xn = x + (size_t)n * C * HW;

  {
    const int pp = t & 15;
    const int cg = t >> 4;
    const int xb = x0 + 2 * pp;

    int xs[4];
    float colm[4];
#pragma unroll
    for (int j = 0; j < 4; ++j) {
      int xa = xb - 1 + j;
      colm[j] = ((unsigned)xa < (unsigned)W) ? 1.f : 0.f;
      xs[j] = xa < 0 ? 0 : (xa > W - 1 ? W - 1 : xa);
    }
    int rowo[3];
    float m[3][4];
#pragma unroll
    for (int r = 0; r < 3; ++r) {
      int yy = y + r - 1;
      float rm = ((unsigned)yy < (unsigned)H) ? 1.f : 0.f;
      int yc = yy < 0 ? 0 : (yy > H - 1 ? H - 1 : yy);
      rowo[r] = yc * W;
#pragma unroll
      for (int j = 0; j < 4; ++j) m[r][j] = rm * colm[j];
    }

    float acc[2][8];
#pragma unroll
    for (int p = 0; p < 8; ++p) { acc[0][p] = 0.f; acc[1][p] = 0.f; }

    for (int c = 0; c < 8; ++c) {
      const int ch = cg * 8 + c;
      const float* xc = xn + (size_t)ch * HW;
      float xv[3][4];
#pragma unroll
      for (int r = 0; r < 3; ++r)
#pragma unroll
        for (int j = 0; j < 4; ++j)
          xv[r][j] = xc[rowo[r] + xs[j]] * m[r][j];

      const float* wc = wg + (size_t)ch * 9;
#pragma unroll
      for (int p = 0; p < 8; ++p) {
        const float* wp = wc + (size_t)p * C * 9;
#pragma unroll
        for (int r = 0; r < 3; ++r) {
#pragma unroll
          for (int kw = 0; kw < 3; ++kw) {
            const float wv = wp[r * 3 + kw];
            acc[0][p] += xv[r][kw] * wv;
            acc[1][p] += xv[r][kw + 1] * wv;
          }
        }
      }
    }
#pragma unroll
    for (int p = 0; p < 8; ++p) {
      lacc[cg][2 * pp][p] = acc[0][p];
      lacc[cg][2 * pp + 1][p] = acc[1][p];
    }
  }
  __syncthreads();

  {
    const int px = t >> 3;
    const int p = t & 7;
    float s = b[p];
#pragma unroll
    for (int g = 0; g < 16; ++g) s += lacc[g][px][p];
    loff[px][p] = s;
  }
  __syncthreads();

  {
    const int px = t & (PXB - 1);
    const int sg = t >> 5;
    const int xx = x0 + px;

    float offv[8];
#pragma unroll
    for (int q = 0; q < 8; ++q) offv[q] = loff[px][q];

    int o00[4], o01[4], o10[4], o11[4];
    float w00[4], w01[4], w10[4], w11[4];
#pragma unroll
    for (int p = 0; p < 4; ++p) {
      float sy = (float)y + offv[2 * p];
      float sx = (float)xx + offv[2 * p + 1];
      float y0f = floorf(sy), x0f = floorf(sx);
      float wy1 = sy - y0f, wx1 = sx - x0f;
      float wy0 = 1.f - wy1, wx0 = 1.f - wx1;
      int iy0 = (int)y0f, ix0 = (int)x0f;
      int iy1 = iy0 + 1, ix1 = ix0 + 1;
      float vy0 = ((unsigned)iy0 < (unsigned)H) ? 1.f : 0.f;
      float vy1 = ((unsigned)iy1 < (unsigned)H) ? 1.f : 0.f;
      float vx0 = ((unsigned)ix0 < (unsigned)W) ? 1.f : 0.f;
      float vx1 = ((unsigned)ix1 < (unsigned)W) ? 1.f : 0.f;
      int cy0 = iy0 < 0 ? 0 : (iy0 > H - 1 ? H - 1 : iy0);
      int cy1 = iy1 < 0 ? 0 : (iy1 > H - 1 ? H - 1 : iy1);
      int cx0 = ix0 < 0 ? 0 : (ix0 > W - 1 ? W - 1 : ix0);
      int cx1 = ix1 < 0 ? 0 : (ix1 > W - 1 ? W - 1 : ix1);
      o00[p] = cy0 * W + cx0; o01[p] = cy0 * W + cx1;
      o10[p] = cy1 * W + cx0; o11[p] = cy1 * W + cx1;
      w00[p] = wy0 * wx0 * vy0 * vx0;
      w01[p] = wy0 * wx1 * vy0 * vx1;
      w10[p] = wy1 * wx0 * vy1 * vx0;
      w11[p] = wy1 * wx1 * vy1 * vx1;
    }

    float* outn = out + (size_t)n * C * (2 * H) * (2 * W);
    for (int c = sg * 16; c < sg * 16 + 16; ++c) {
      const float* xc = xn + (size_t)c * HW;
      float s[4];
#pragma unroll
      for (int p = 0; p < 4; ++p) {
        s[p] = w00[p] * xc[o00[p]] + w01[p] * xc[o01[p]] +
               w10[p] * xc[o10[p]] + w11[p] * xc[o11[p]];
      }
      float* oc = outn + (size_t)c * (2 * H) * (2 * W);
      float2* r0 = (float2*)(oc + (size_t)(2 * y) * (2 * W) + 2 * xx);
      float2* r1 = (float2*)(oc + (size_t)(2 * y + 1) * (2 * W) + 2 * xx);
      *r0 = make_float2(s[0], s[1]);
      *r1 = make_float2(s[2], s[3]);
    }
  }
}

extern "C" void kernel_launch(void* const* d_in, const int* in_sizes, int n_in,
                              void* d_out, int out_size, void* d_ws, size_t ws_size,
                              hipStream_t stream) {
  const float* x = (const float*)d_in[0];
  const float* w = (const float*)d_in[1];
  const float* b = (const float*)d_in[2];
  float* out = (float*)d_out;

  const size_t xt_bytes = (size_t)NB * HW * C * sizeof(float);   // 32 MB
  const size_t wt_bytes = (size_t)8 * C * 9 * sizeof(float);     // 36 KB
  dim3 block(256);

  if (d_ws != nullptr && ws_size >= xt_bytes + wt_bytes) {
    float* xt = (float*)d_ws;
    float* wt = (float*)((char*)d_ws + xt_bytes);
    prep_wt<<<dim3(36), block, 0, stream>>>(w, wt);
    transpose_nchw_nhwc<<<dim3(NB * (HW / TPX)), block, 0, stream>>>(x, xt);
    dcn_fused_t7<<<dim3(NB * H * NSEG), block, 0, stream>>>(xt, wt, b, out);
  } else {
    dcn_fused<<<dim3(NB * H * NSEG), block, 0, stream>>>(x, w, b, out);
  }
}

// Round 9
// 209.806 us; speedup vs baseline: 1.4710x; 1.4710x over previous
//
#include <hip/hip_runtime.h>

#define H 128
#define W 128
#define C 128
#define NB 4
#define HW (H * W)
#define PXB 32            // pixels per block (quarter row)
#define NSEG (W / PXB)    // 4
#define TPX 64            // pixels per transpose block

// ---------------------------------------------------------------------------
// Pre-pass 1: NCHW -> NHWC transpose of x into workspace (32 MB).
// ---------------------------------------------------------------------------
__global__ __launch_bounds__(256) void transpose_nchw_nhwc(
    const float* __restrict__ x, float* __restrict__ xt) {
  __shared__ float tile[TPX][C + 1];  // 64 x 129 floats = 33 KB
  const int blk = blockIdx.x;
  const int n = blk >> 8;                 // HW/TPX = 256 blocks per image
  const int p0 = (blk & 255) * TPX;
  const float* xn = x + (size_t)n * C * HW;
  float* xtn = xt + (size_t)n * HW * C;

  const int i = threadIdx.x & 63;         // pixel within tile
  const int c0 = threadIdx.x >> 6;        // 0..3
#pragma unroll
  for (int c = c0; c < C; c += 4)
    tile[i][c] = xn[(size_t)c * HW + p0 + i];
  __syncthreads();

  const int cl = threadIdx.x & 31;        // channel quad 0..31
  const int pr = threadIdx.x >> 5;        // 0..7
#pragma unroll
  for (int p = pr; p < TPX; p += 8) {
    float4 v = make_float4(tile[p][4 * cl + 0], tile[p][4 * cl + 1],
                           tile[p][4 * cl + 2], tile[p][4 * cl + 3]);
    *(float4*)(xtn + (size_t)(p0 + p) * C + 4 * cl) = v;
  }
}

// ---------------------------------------------------------------------------
// Pre-pass 2: weight re-layout for lane-contiguous LDS reads.
// lw4 float4 element [((ch*9+k)*2+g)*32+q] = w_off[p=4g+c][channel 4q+ch][k]
// for c = 0..3 within the float4.  9216 floats total (36.9 KB).
// ---------------------------------------------------------------------------
__global__ __launch_bounds__(256) void prep_wt2(
    const float* __restrict__ wg, float* __restrict__ wt2) {
  const int i = blockIdx.x * 256 + threadIdx.x;  // 36 x 256 = 9216
  const int c = i & 3;
  int r = i >> 2;
  const int q = r & 31; r >>= 5;
  const int g = r & 1;  r >>= 1;
  const int k = r % 9;
  const int ch = r / 9;                          // 0..3
  wt2[i] = wg[((size_t)(4 * g + c) * C + 4 * q + ch) * 9 + k];
}

// ---------------------------------------------------------------------------
// Fused deformable-conv t8 = channel-major conv + t3 phase 2 (verbatim).
//  Conv: thread (q = t&31 channel-quad, s = t>>5 pixel-octet). Tap loads are
//  lane-contiguous 512B rows (1 line per 4-lane quad: 18 instr vs t3's 24
//  instr x 4 lines/quad). Weights from LDS (staged once, contiguous-by-lane).
//  Per-thread acc[4px][8p] partials dumped to LDS (stride 257, conflict-free
//  scalar) and reduced. Phase 1.75 / phase 2: t3 verbatim.
// LDS: single 2304-float4 buffer (36864 B), regions aliased by phase:
//  conv:   lw4      f4[0..2304)
//  dump:   accl     floats [0..8223)  (f4 [0..2056))
//  reduce: loff     f4 [2056..2128)   (floats, stride 9)
//  tables: ltapi    f4 [0..128), ltapw f4 [128..256)
//  restage:lout     f4 [256..1312)    (stride 33)
// ---------------------------------------------------------------------------
__global__ __launch_bounds__(256, 4) void dcn_fused_t8(
    const float* __restrict__ xt, const float* __restrict__ wt2,
    const float* __restrict__ b, float* __restrict__ out) {

  __shared__ __align__(16) float4 lsh4[2304];

  const int t = threadIdx.x;
  const int bxr = blockIdx.x;
  const int bx = ((bxr & 7) << 8) | (bxr >> 3);  // XCD swizzle (2048 = 8*256)
  const int seg = bx & (NSEG - 1);
  const int y = (bx >> 2) & (H - 1);
  const int n = bx >> 9;
  const int x0 = seg * PXB;

  const float* xtn = xt + (size_t)n * HW * C;

  // ---------------- Stage weights into LDS ---------------------------------
  {
    const float4* w4 = (const float4*)wt2;
#pragma unroll
    for (int i = 0; i < 9; ++i)
      lsh4[t + 256 * i] = w4[t + 256 * i];
  }
  __syncthreads();

  // ---------------- Phase 1: conv, channel-major lanes ---------------------
  {
    const int q = t & 31;        // channel quad (lane-contiguous loads)
    const int s = t >> 5;        // pixel octet: pixels 4s..4s+3
    const int xb = x0 + 4 * s;

    int xs[6];
    float colm[6];
#pragma unroll
    for (int j = 0; j < 6; ++j) {
      int xa = xb - 1 + j;
      colm[j] = ((unsigned)xa < (unsigned)W) ? 1.f : 0.f;
      xs[j] = xa < 0 ? 0 : (xa > W - 1 ? W - 1 : xa);
    }

    float acc[4][8];
#pragma unroll
    for (int px = 0; px < 4; ++px)
#pragma unroll
      for (int p = 0; p < 8; ++p) acc[px][p] = 0.f;

#pragma unroll
    for (int r = 0; r < 3; ++r) {
      int yy = y + r - 1;
      float rmv = ((unsigned)yy < (unsigned)H) ? 1.f : 0.f;
      int yc = yy < 0 ? 0 : (yy > H - 1 ? H - 1 : yy);
      const float* xrow = xtn + (size_t)yc * W * C + 4 * q;
      float tap[6][4];
#pragma unroll
      for (int j = 0; j < 6; ++j) {
        float4 v = *(const float4*)(xrow + (size_t)xs[j] * C);
        const float mm = rmv * colm[j];
        tap[j][0] = v.x * mm; tap[j][1] = v.y * mm;
        tap[j][2] = v.z * mm; tap[j][3] = v.w * mm;
      }
#pragma unroll
      for (int kw = 0; kw < 3; ++kw) {
        const int k = 3 * r + kw;
#pragma unroll
        for (int ch = 0; ch < 4; ++ch) {
          const float4 wa = lsh4[((ch * 9 + k) * 2 + 0) * 32 + q];  // p 0..3
          const float4 wb = lsh4[((ch * 9 + k) * 2 + 1) * 32 + q];  // p 4..7
#pragma unroll
          for (int px = 0; px < 4; ++px) {
            const float tv = tap[kw + px][ch];
            acc[px][0] += tv * wa.x; acc[px][1] += tv * wa.y;
            acc[px][2] += tv * wa.z; acc[px][3] += tv * wa.w;
            acc[px][4] += tv * wb.x; acc[px][5] += tv * wb.y;
            acc[px][6] += tv * wb.z; acc[px][7] += tv * wb.w;
          }
        }
      }
    }

    __syncthreads();  // weights dead; accl aliases the region
    // dump partials: accl[q-stride 257][32s + 8px + p] (scalar, conflict-free)
    float* accl = (float*)lsh4;
    const int base = 257 * q + 32 * s;
#pragma unroll
    for (int px = 0; px < 4; ++px)
#pragma unroll
      for (int p = 0; p < 8; ++p)
        accl[base + 8 * px + p] = acc[px][p];
  }
  __syncthreads();

  // ---------------- Phase 1.5: reduce 32 q-lanes + bias --------------------
  {
    const float* accl = (const float*)lsh4;
    float* loff = (float*)(lsh4 + 2056);
    const int px = t >> 3;  // 0..31
    const int p = t & 7;
    const int c = 32 * (px >> 2) + 8 * (px & 3) + p;
    float s = b[p];
#pragma unroll
    for (int q = 0; q < 32; ++q) s += accl[257 * q + c];
    loff[px * 9 + p] = s;
  }
  __syncthreads();

  // ---------------- Phase 1.75: per (px,pos) tap table (t3) ----------------
  if (t < 128) {
    const float* loff = (const float*)(lsh4 + 2056);
    int4* ltapi = (int4*)lsh4;
    float4* ltapw = lsh4 + 128;
    const int px = t >> 2;
    const int pos = t & 3;
    const int xx = x0 + px;
    float sy = (float)y + loff[px * 9 + 2 * pos];
    float sx = (float)xx + loff[px * 9 + 2 * pos + 1];
    float y0f = floorf(sy), x0f = floorf(sx);
    float wy1 = sy - y0f, wx1 = sx - x0f;
    float wy0 = 1.f - wy1, wx0 = 1.f - wx1;
    int iy0 = (int)y0f, ix0 = (int)x0f;
    int iy1 = iy0 + 1, ix1 = ix0 + 1;
    float vy0 = ((unsigned)iy0 < (unsigned)H) ? 1.f : 0.f;
    float vy1 = ((unsigned)iy1 < (unsigned)H) ? 1.f : 0.f;
    float vx0 = ((unsigned)ix0 < (unsigned)W) ? 1.f : 0.f;
    float vx1 = ((unsigned)ix1 < (unsigned)W) ? 1.f : 0.f;
    int cy0 = iy0 < 0 ? 0 : (iy0 > H - 1 ? H - 1 : iy0);
    int cy1 = iy1 < 0 ? 0 : (iy1 > H - 1 ? H - 1 : iy1);
    int cx0 = ix0 < 0 ? 0 : (ix0 > W - 1 ? W - 1 : ix0);
    int cx1 = ix1 < 0 ? 0 : (ix1 > W - 1 ? W - 1 : ix1);
    ltapi[px * 4 + pos] = make_int4(cy0 * W + cx0, cy0 * W + cx1,
                                    cy1 * W + cx0, cy1 * W + cx1);
    ltapw[px * 4 + pos] = make_float4(wy0 * wx0 * vy0 * vx0, wy0 * wx1 * vy0 * vx1,
                                      wy1 * wx0 * vy1 * vx0, wy1 * wx1 * vy1 * vx1);
  }
  __syncthreads();

  // ---------------- Phase 2: t3 verbatim (gather + restage + store) --------
  {
    const int4* ltapi = (const int4*)lsh4;
    const float4* ltapw = lsh4 + 128;
    float4* lout4 = lsh4 + 256;          // [4][8][33] float4
    const int cq = t & 31;   // channel quad
    const int pg = t >> 5;   // pixel-in-pass 0..7
    const int spx = t & 7;   // store px-in-pass
    const int cg4 = t >> 3;  // store channel quad 0..31
    const float4* xt4 = (const float4*)xtn;
    float* outn = out + (size_t)n * C * (2 * H) * (2 * W);

    for (int pass = 0; pass < 4; ++pass) {
      const int px = pass * 8 + pg;
      float4 sacc[4];
#pragma unroll
      for (int pos = 0; pos < 4; ++pos) {
        const int4 o = ltapi[px * 4 + pos];
        const float4 wv = ltapw[px * 4 + pos];
        float4 v00 = xt4[(size_t)o.x * (C / 4) + cq];
        float4 v01 = xt4[(size_t)o.y * (C / 4) + cq];
        float4 v10 = xt4[(size_t)o.z * (C / 4) + cq];
        float4 v11 = xt4[(size_t)o.w * (C / 4) + cq];
        sacc[pos].x = wv.x * v00.x + wv.y * v01.x + wv.z * v10.x + wv.w * v11.x;
        sacc[pos].y = wv.x * v00.y + wv.y * v01.y + wv.z * v10.y + wv.w * v11.y;
        sacc[pos].z = wv.x * v00.z + wv.y * v01.z + wv.z * v10.z + wv.w * v11.z;
        sacc[pos].w = wv.x * v00.w + wv.y * v01.w + wv.z * v10.w + wv.w * v11.w;
      }
      __syncthreads();  // WAR: previous pass's lout reads done
#pragma unroll
      for (int pos = 0; pos < 4; ++pos)
        lout4[(pos * 8 + pg) * 33 + cq] = sacc[pos];
      __syncthreads();

      // store: px-major coalesced float2
      float4 v[4];
#pragma unroll
      for (int pos = 0; pos < 4; ++pos)
        v[pos] = lout4[(pos * 8 + spx) * 33 + cg4];
      const int xg = x0 + pass * 8 + spx;
      float* obase = outn + (size_t)(2 * y) * (2 * W) + 2 * xg;
#define STORE_CH(J, CMP)                                                      \
      {                                                                       \
        float* oc = obase + (size_t)(cg4 * 4 + J) * (4 * HW);                 \
        *(float2*)oc = make_float2(v[0].CMP, v[1].CMP);                       \
        *(float2*)(oc + 2 * W) = make_float2(v[2].CMP, v[3].CMP);             \
      }
      STORE_CH(0, x) STORE_CH(1, y) STORE_CH(2, z) STORE_CH(3, w)
#undef STORE_CH
    }
  }
}

// ---------------------------------------------------------------------------
// Fallback: original NCHW-gather kernel (used only if workspace too small).
// ---------------------------------------------------------------------------
__global__ __launch_bounds__(256) void dcn_fused(
    const float* __restrict__ x, const float* __restrict__ wg,
    const float* __restrict__ b, float* __restrict__ out) {

  __shared__ float lacc[16][PXB][8];
  __shared__ float loff[PXB][9];

  const int t = threadIdx.x;
  const int bx = blockIdx.x;
  const int seg = bx & (NSEG - 1);
  const int y = (bx >> 2) & (H - 1);
  const int n = bx >> 9;
  const int x0 = seg * PXB;

  const float* xn = x + (size_t)n * C * HW;

  {
    const int pp = t & 15;
    const int cg = t >> 4;
    const int xb = x0 + 2 * pp;

    int xs[4];
    float colm[4];
#pragma unroll
    for (int j = 0; j < 4; ++j) {
      int xa = xb - 1 + j;
      colm[j] = ((unsigned)xa < (unsigned)W) ? 1.f : 0.f;
      xs[j] = xa < 0 ? 0 : (xa > W - 1 ? W - 1 : xa);
    }
    int rowo[3];
    float m[3][4];
#pragma unroll
    for (int r = 0; r < 3; ++r) {
      int yy = y + r - 1;
      float rm = ((unsigned)yy < (unsigned)H) ? 1.f : 0.f;
      int yc = yy < 0 ? 0 : (yy > H - 1 ? H - 1 : yy);
      rowo[r] = yc * W;
#pragma unroll
      for (int j = 0; j < 4; ++j) m[r][j] = rm * colm[j];
    }

    float acc[2][8];
#pragma unroll
    for (int p = 0; p < 8; ++p) { acc[0][p] = 0.f; acc[1][p] = 0.f; }

    for (int c = 0; c < 8; ++c) {
      const int ch = cg * 8 + c;
      const float* xc = xn + (size_t)ch * HW;
      float xv[3][4];
#pragma unroll
      for (int r = 0; r < 3; ++r)
#pragma unroll
        for (int j = 0; j < 4; ++j)
          xv[r][j] = xc[rowo[r] + xs[j]] * m[r][j];

      const float* wc = wg + (size_t)ch * 9;
#pragma unroll
      for (int p = 0; p < 8; ++p) {
        const float* wp = wc + (size_t)p * C * 9;
#pragma unroll
        for (int r = 0; r < 3; ++r) {
#pragma unroll
          for (int kw = 0; kw < 3; ++kw) {
            const float wv = wp[r * 3 + kw];
            acc[0][p] += xv[r][kw] * wv;
            acc[1][p] += xv[r][kw + 1] * wv;
          }
        }
      }
    }
#pragma unroll
    for (int p = 0; p < 8; ++p) {
      lacc[cg][2 * pp][p] = acc[0][p];
      lacc[cg][2 * pp + 1][p] = acc[1][p];
    }
  }
  __syncthreads();

  {
    const int px = t >> 3;
    const int p = t & 7;
    float s = b[p];
#pragma unroll
    for (int g = 0; g < 16; ++g) s += lacc[g][px][p];
    loff[px][p] = s;
  }
  __syncthreads();

  {
    const int px = t & (PXB - 1);
    const int sg = t >> 5;
    const int xx = x0 + px;

    float offv[8];
#pragma unroll
    for (int q = 0; q < 8; ++q) offv[q] = loff[px][q];

    int o00[4], o01[4], o10[4], o11[4];
    float w00[4], w01[4], w10[4], w11[4];
#pragma unroll
    for (int p = 0; p < 4; ++p) {
      float sy = (float)y + offv[2 * p];
      float sx = (float)xx + offv[2 * p + 1];
      float y0f = floorf(sy), x0f = floorf(sx);
      float wy1 = sy - y0f, wx1 = sx - x0f;
      float wy0 = 1.f - wy1, wx0 = 1.f - wx1;
      int iy0 = (int)y0f, ix0 = (int)x0f;
      int iy1 = iy0 + 1, ix1 = ix0 + 1;
      float vy0 = ((unsigned)iy0 < (unsigned)H) ? 1.f : 0.f;
      float vy1 = ((unsigned)iy1 < (unsigned)H) ? 1.f : 0.f;
      float vx0 = ((unsigned)ix0 < (unsigned)W) ? 1.f : 0.f;
      float vx1 = ((unsigned)ix1 < (unsigned)W) ? 1.f : 0.f;
      int cy0 = iy0 < 0 ? 0 : (iy0 > H - 1 ? H - 1 : iy0);
      int cy1 = iy1 < 0 ? 0 : (iy1 > H - 1 ? H - 1 : iy1);
      int cx0 = ix0 < 0 ? 0 : (ix0 > W - 1 ? W - 1 : ix0);
      int cx1 = ix1 < 0 ? 0 : (ix1 > W - 1 ? W - 1 : ix1);
      o00[p] = cy0 * W + cx0; o01[p] = cy0 * W + cx1;
      o10[p] = cy1 * W + cx0; o11[p] = cy1 * W + cx1;
      w00[p] = wy0 * wx0 * vy0 * vx0;
      w01[p] = wy0 * wx1 * vy0 * vx1;
      w10[p] = wy1 * wx0 * vy1 * vx0;
      w11[p] = wy1 * wx1 * vy1 * vx1;
    }

    float* outn = out + (size_t)n * C * (2 * H) * (2 * W);
    for (int c = sg * 16; c < sg * 16 + 16; ++c) {
      const float* xc = xn + (size_t)c * HW;
      float s[4];
#pragma unroll
      for (int p = 0; p < 4; ++p) {
        s[p] = w00[p] * xc[o00[p]] + w01[p] * xc[o01[p]] +
               w10[p] * xc[o10[p]] + w11[p] * xc[o11[p]];
      }
      float* oc = outn + (size_t)c * (2 * H) * (2 * W);
      float2* r0 = (float2*)(oc + (size_t)(2 * y) * (2 * W) + 2 * xx);
      float2* r1 = (float2*)(oc + (size_t)(2 * y + 1) * (2 * W) + 2 * xx);
      *r0 = make_float2(s[0], s[1]);
      *r1 = make_float2(s[2], s[3]);
    }
  }
}

extern "C" void kernel_launch(void* const* d_in, const int* in_sizes, int n_in,
                              void* d_out, int out_size, void* d_ws, size_t ws_size,
                              hipStream_t stream) {
  const float* x = (const float*)d_in[0];
  const float* w = (const float*)d_in[1];
  const float* b = (const float*)d_in[2];
  float* out = (float*)d_out;

  const size_t xt_bytes = (size_t)NB * HW * C * sizeof(float);   // 32 MB
  const size_t wt_bytes = (size_t)9216 * sizeof(float);          // 36.9 KB
  dim3 block(256);

  if (d_ws != nullptr && ws_size >= xt_bytes + wt_bytes) {
    float* xt = (float*)d_ws;
    float* wt2 = (float*)((char*)d_ws + xt_bytes);
    prep_wt2<<<dim3(36), block, 0, stream>>>(w, wt2);
    transpose_nchw_nhwc<<<dim3(NB * (HW / TPX)), block, 0, stream>>>(x, xt);
    dcn_fused_t8<<<dim3(NB * H * NSEG), block, 0, stream>>>(xt, wt2, b, out);
  } else {
    dcn_fused<<<dim3(NB * H * NSEG), block, 0, stream>>>(x, w, b, out);
  }
}

// Round 10
// 194.259 us; speedup vs baseline: 1.5887x; 1.0800x over previous
//
#include <hip/hip_runtime.h>

#define H 128
#define W 128
#define C 128
#define NB 4
#define HW (H * W)
#define PXB 32            // pixels per block (quarter row)
#define NSEG (W / PXB)    // 4
#define TPX 64            // pixels per transpose block

// ---------------------------------------------------------------------------
// Pre-pass 1: NCHW -> NHWC transpose of x into workspace (32 MB).
// ---------------------------------------------------------------------------
__global__ __launch_bounds__(256) void transpose_nchw_nhwc(
    const float* __restrict__ x, float* __restrict__ xt) {
  __shared__ float tile[TPX][C + 1];  // 64 x 129 floats = 33 KB
  const int blk = blockIdx.x;
  const int n = blk >> 8;                 // HW/TPX = 256 blocks per image
  const int p0 = (blk & 255) * TPX;
  const float* xn = x + (size_t)n * C * HW;
  float* xtn = xt + (size_t)n * HW * C;

  const int i = threadIdx.x & 63;         // pixel within tile
  const int c0 = threadIdx.x >> 6;        // 0..3
#pragma unroll
  for (int c = c0; c < C; c += 4)
    tile[i][c] = xn[(size_t)c * HW + p0 + i];
  __syncthreads();

  const int cl = threadIdx.x & 31;        // channel quad 0..31
  const int pr = threadIdx.x >> 5;        // 0..7
#pragma unroll
  for (int p = pr; p < TPX; p += 8) {
    float4 v = make_float4(tile[p][4 * cl + 0], tile[p][4 * cl + 1],
                           tile[p][4 * cl + 2], tile[p][4 * cl + 3]);
    *(float4*)(xtn + (size_t)(p0 + p) * C + 4 * cl) = v;
  }
}

// ---------------------------------------------------------------------------
// Pre-pass 2: weight re-layout for lane-contiguous LDS reads.
// lw4 float4 element [((ch*9+k)*2+g)*32+q] = w_off[p=4g+c][channel 4q+ch][k]
// for c = 0..3 within the float4.  9216 floats total (36.9 KB).
// ---------------------------------------------------------------------------
__global__ __launch_bounds__(256) void prep_wt2(
    const float* __restrict__ wg, float* __restrict__ wt2) {
  const int i = blockIdx.x * 256 + threadIdx.x;  // 36 x 256 = 9216
  const int c = i & 3;
  int r = i >> 2;
  const int q = r & 31; r >>= 5;
  const int g = r & 1;  r >>= 1;
  const int k = r % 9;
  const int ch = r / 9;                          // 0..3
  wt2[i] = wg[((size_t)(4 * g + c) * C + 4 * q + ch) * 9 + k];
}

// ---------------------------------------------------------------------------
// Fused deformable-conv t9 = t8 with __launch_bounds__(256, 2).
//  Round-9 evidence: (256,4) makes the compiler cap VGPR at 64; t8's conv
//  (acc[4][8] + tap[6][4]) needs ~80-100 live -> 63 MB scratch writes +
//  32 MB scratch reads.  (256,2) empirically allows 128 VGPR (t6).  LDS is
//  36.9 KB -> 4 blocks/CU either way, so occupancy is unchanged; the spill
//  is the only thing that changes.  Everything below is t8 byte-identical.
// ---------------------------------------------------------------------------
__global__ __launch_bounds__(256, 2) void dcn_fused_t9(
    const float* __restrict__ xt, const float* __restrict__ wt2,
    const float* __restrict__ b, float* __restrict__ out) {

  __shared__ __align__(16) float4 lsh4[2304];

  const int t = threadIdx.x;
  const int bxr = blockIdx.x;
  const int bx = ((bxr & 7) << 8) | (bxr >> 3);  // XCD swizzle (2048 = 8*256)
  const int seg = bx & (NSEG - 1);
  const int y = (bx >> 2) & (H - 1);
  const int n = bx >> 9;
  const int x0 = seg * PXB;

  const float* xtn = xt + (size_t)n * HW * C;

  // ---------------- Stage weights into LDS ---------------------------------
  {
    const float4* w4 = (const float4*)wt2;
#pragma unroll
    for (int i = 0; i < 9; ++i)
      lsh4[t + 256 * i] = w4[t + 256 * i];
  }
  __syncthreads();

  // ---------------- Phase 1: conv, channel-major lanes ---------------------
  {
    const int q = t & 31;        // channel quad (lane-contiguous loads)
    const int s = t >> 5;        // pixel octet: pixels 4s..4s+3
    const int xb = x0 + 4 * s;

    int xs[6];
    float colm[6];
#pragma unroll
    for (int j = 0; j < 6; ++j) {
      int xa = xb - 1 + j;
      colm[j] = ((unsigned)xa < (unsigned)W) ? 1.f : 0.f;
      xs[j] = xa < 0 ? 0 : (xa > W - 1 ? W - 1 : xa);
    }

    float acc[4][8];
#pragma unroll
    for (int px = 0; px < 4; ++px)
#pragma unroll
      for (int p = 0; p < 8; ++p) acc[px][p] = 0.f;

#pragma unroll
    for (int r = 0; r < 3; ++r) {
      int yy = y + r - 1;
      float rmv = ((unsigned)yy < (unsigned)H) ? 1.f : 0.f;
      int yc = yy < 0 ? 0 : (yy > H - 1 ? H - 1 : yy);
      const float* xrow = xtn + (size_t)yc * W * C + 4 * q;
      float tap[6][4];
#pragma unroll
      for (int j = 0; j < 6; ++j) {
        float4 v = *(const float4*)(xrow + (size_t)xs[j] * C);
        const float mm = rmv * colm[j];
        tap[j][0] = v.x * mm; tap[j][1] = v.y * mm;
        tap[j][2] = v.z * mm; tap[j][3] = v.w * mm;
      }
#pragma unroll
      for (int kw = 0; kw < 3; ++kw) {
        const int k = 3 * r + kw;
#pragma unroll
        for (int ch = 0; ch < 4; ++ch) {
          const float4 wa = lsh4[((ch * 9 + k) * 2 + 0) * 32 + q];  // p 0..3
          const float4 wb = lsh4[((ch * 9 + k) * 2 + 1) * 32 + q];  // p 4..7
#pragma unroll
          for (int px = 0; px < 4; ++px) {
            const float tv = tap[kw + px][ch];
            acc[px][0] += tv * wa.x; acc[px][1] += tv * wa.y;
            acc[px][2] += tv * wa.z; acc[px][3] += tv * wa.w;
            acc[px][4] += tv * wb.x; acc[px][5] += tv * wb.y;
            acc[px][6] += tv * wb.z; acc[px][7] += tv * wb.w;
          }
        }
      }
    }

    __syncthreads();  // weights dead; accl aliases the region
    // dump partials: accl[q-stride 257][32s + 8px + p] (scalar, conflict-free)
    float* accl = (float*)lsh4;
    const int base = 257 * q + 32 * s;
#pragma unroll
    for (int px = 0; px < 4; ++px)
#pragma unroll
      for (int p = 0; p < 8; ++p)
        accl[base + 8 * px + p] = acc[px][p];
  }
  __syncthreads();

  // ---------------- Phase 1.5: reduce 32 q-lanes + bias --------------------
  {
    const float* accl = (const float*)lsh4;
    float* loff = (float*)(lsh4 + 2056);
    const int px = t >> 3;  // 0..31
    const int p = t & 7;
    const int c = 32 * (px >> 2) + 8 * (px & 3) + p;
    float s = b[p];
#pragma unroll
    for (int q = 0; q < 32; ++q) s += accl[257 * q + c];
    loff[px * 9 + p] = s;
  }
  __syncthreads();

  // ---------------- Phase 1.75: per (px,pos) tap table (t3) ----------------
  if (t < 128) {
    const float* loff = (const float*)(lsh4 + 2056);
    int4* ltapi = (int4*)lsh4;
    float4* ltapw = lsh4 + 128;
    const int px = t >> 2;
    const int pos = t & 3;
    const int xx = x0 + px;
    float sy = (float)y + loff[px * 9 + 2 * pos];
    float sx = (float)xx + loff[px * 9 + 2 * pos + 1];
    float y0f = floorf(sy), x0f = floorf(sx);
    float wy1 = sy - y0f, wx1 = sx - x0f;
    float wy0 = 1.f - wy1, wx0 = 1.f - wx1;
    int iy0 = (int)y0f, ix0 = (int)x0f;
    int iy1 = iy0 + 1, ix1 = ix0 + 1;
    float vy0 = ((unsigned)iy0 < (unsigned)H) ? 1.f : 0.f;
    float vy1 = ((unsigned)iy1 < (unsigned)H) ? 1.f : 0.f;
    float vx0 = ((unsigned)ix0 < (unsigned)W) ? 1.f : 0.f;
    float vx1 = ((unsigned)ix1 < (unsigned)W) ? 1.f : 0.f;
    int cy0 = iy0 < 0 ? 0 : (iy0 > H - 1 ? H - 1 : iy0);
    int cy1 = iy1 < 0 ? 0 : (iy1 > H - 1 ? H - 1 : iy1);
    int cx0 = ix0 < 0 ? 0 : (ix0 > W - 1 ? W - 1 : ix0);
    int cx1 = ix1 < 0 ? 0 : (ix1 > W - 1 ? W - 1 : ix1);
    ltapi[px * 4 + pos] = make_int4(cy0 * W + cx0, cy0 * W + cx1,
                                    cy1 * W + cx0, cy1 * W + cx1);
    ltapw[px * 4 + pos] = make_float4(wy0 * wx0 * vy0 * vx0, wy0 * wx1 * vy0 * vx1,
                                      wy1 * wx0 * vy1 * vx0, wy1 * wx1 * vy1 * vx1);
  }
  __syncthreads();

  // ---------------- Phase 2: t3 verbatim (gather + restage + store) --------
  {
    const int4* ltapi = (const int4*)lsh4;
    const float4* ltapw = lsh4 + 128;
    float4* lout4 = lsh4 + 256;          // [4][8][33] float4
    const int cq = t & 31;   // channel quad
    const int pg = t >> 5;   // pixel-in-pass 0..7
    const int spx = t & 7;   // store px-in-pass
    const int cg4 = t >> 3;  // store channel quad 0..31
    const float4* xt4 = (const float4*)xtn;
    float* outn = out + (size_t)n * C * (2 * H) * (2 * W);

    for (int pass = 0; pass < 4; ++pass) {
      const int px = pass * 8 + pg;
      float4 sacc[4];
#pragma unroll
      for (int pos = 0; pos < 4; ++pos) {
        const int4 o = ltapi[px * 4 + pos];
        const float4 wv = ltapw[px * 4 + pos];
        float4 v00 = xt4[(size_t)o.x * (C / 4) + cq];
        float4 v01 = xt4[(size_t)o.y * (C / 4) + cq];
        float4 v10 = xt4[(size_t)o.z * (C / 4) + cq];
        float4 v11 = xt4[(size_t)o.w * (C / 4) + cq];
        sacc[pos].x = wv.x * v00.x + wv.y * v01.x + wv.z * v10.x + wv.w * v11.x;
        sacc[pos].y = wv.x * v00.y + wv.y * v01.y + wv.z * v10.y + wv.w * v11.y;
        sacc[pos].z = wv.x * v00.z + wv.y * v01.z + wv.z * v10.z + wv.w * v11.z;
        sacc[pos].w = wv.x * v00.w + wv.y * v01.w + wv.z * v10.w + wv.w * v11.w;
      }
      __syncthreads();  // WAR: previous pass's lout reads done
#pragma unroll
      for (int pos = 0; pos < 4; ++pos)
        lout4[(pos * 8 + pg) * 33 + cq] = sacc[pos];
      __syncthreads();

      // store: px-major coalesced float2
      float4 v[4];
#pragma unroll
      for (int pos = 0; pos < 4; ++pos)
        v[pos] = lout4[(pos * 8 + spx) * 33 + cg4];
      const int xg = x0 + pass * 8 + spx;
      float* obase = outn + (size_t)(2 * y) * (2 * W) + 2 * xg;
#define STORE_CH(J, CMP)                                                      \
      {                                                                       \
        float* oc = obase + (size_t)(cg4 * 4 + J) * (4 * HW);                 \
        *(float2*)oc = make_float2(v[0].CMP, v[1].CMP);                       \
        *(float2*)(oc + 2 * W) = make_float2(v[2].CMP, v[3].CMP);             \
      }
      STORE_CH(0, x) STORE_CH(1, y) STORE_CH(2, z) STORE_CH(3, w)
#undef STORE_CH
    }
  }
}

// ---------------------------------------------------------------------------
// Fallback: original NCHW-gather kernel (used only if workspace too small).
// ---------------------------------------------------------------------------
__global__ __launch_bounds__(256) void dcn_fused(
    const float* __restrict__ x, const float* __restrict__ wg,
    const float* __restrict__ b, float* __restrict__ out) {

  __shared__ float lacc[16][PXB][8];
  __shared__ float loff[PXB][9];

  const int t = threadIdx.x;
  const int bx = blockIdx.x;
  const int seg = bx & (NSEG - 1);
  const int y = (bx >> 2) & (H - 1);
  const int n = bx >> 9;
  const int x0 = seg * PXB;

  const float* xn = x + (size_t)n * C * HW;

  {
    const int pp = t & 15;
    const int cg = t >> 4;
    const int xb = x0 + 2 * pp;

    int xs[4];
    float colm[4];
#pragma unroll
    for (int j = 0; j < 4; ++j) {
      int xa = xb - 1 + j;
      colm[j] = ((unsigned)xa < (unsigned)W) ? 1.f : 0.f;
      xs[j] = xa < 0 ? 0 : (xa > W - 1 ? W - 1 : xa);
    }
    int rowo[3];
    float m[3][4];
#pragma unroll
    for (int r = 0; r < 3; ++r) {
      int yy = y + r - 1;
      float rm = ((unsigned)yy < (unsigned)H) ? 1.f : 0.f;
      int yc = yy < 0 ? 0 : (yy > H - 1 ? H - 1 : yy);
      rowo[r] = yc * W;
#pragma unroll
      for (int j = 0; j < 4; ++j) m[r][j] = rm * colm[j];
    }

    float acc[2][8];
#pragma unroll
    for (int p = 0; p < 8; ++p) { acc[0][p] = 0.f; acc[1][p] = 0.f; }

    for (int c = 0; c < 8; ++c) {
      const int ch = cg * 8 + c;
      const float* xc = xn + (size_t)ch * HW;
      float xv[3][4];
#pragma unroll
      for (int r = 0; r < 3; ++r)
#pragma unroll
        for (int j = 0; j < 4; ++j)
          xv[r][j] = xc[rowo[r] + xs[j]] * m[r][j];

      const float* wc = wg + (size_t)ch * 9;
#pragma unroll
      for (int p = 0; p < 8; ++p) {
        const float* wp = wc + (size_t)p * C * 9;
#pragma unroll
        for (int r = 0; r < 3; ++r) {
#pragma unroll
          for (int kw = 0; kw < 3; ++kw) {
            const float wv = wp[r * 3 + kw];
            acc[0][p] += xv[r][kw] * wv;
            acc[1][p] += xv[r][kw + 1] * wv;
          }
        }
      }
    }
#pragma unroll
    for (int p = 0; p < 8; ++p) {
      lacc[cg][2 * pp][p] = acc[0][p];
      lacc[cg][2 * pp + 1][p] = acc[1][p];
    }
  }
  __syncthreads();

  {
    const int px = t >> 3;
    const int p = t & 7;
    float s = b[p];
#pragma unroll
    for (int g = 0; g < 16; ++g) s += lacc[g][px][p];
    loff[px][p] = s;
  }
  __syncthreads();

  {
    const int px = t & (PXB - 1);
    const int sg = t >> 5;
    const int xx = x0 + px;

    float offv[8];
#pragma unroll
    for (int q = 0; q < 8; ++q) offv[q] = loff[px][q];

    int o00[4], o01[4], o10[4], o11[4];
    float w00[4], w01[4], w10[4], w11[4];
#pragma unroll
    for (int p = 0; p < 4; ++p) {
      float sy = (float)y + offv[2 * p];
      float sx = (float)xx + offv[2 * p + 1];
      float y0f = floorf(sy), x0f = floorf(sx);
      float wy1 = sy - y0f, wx1 = sx - x0f;
      float wy0 = 1.f - wy1, wx0 = 1.f - wx1;
      int iy0 = (int)y0f, ix0 = (int)x0f;
      int iy1 = iy0 + 1, ix1 = ix0 + 1;
      float vy0 = ((unsigned)iy0 < (unsigned)H) ? 1.f : 0.f;
      float vy1 = ((unsigned)iy1 < (unsigned)H) ? 1.f : 0.f;
      float vx0 = ((unsigned)ix0 < (unsigned)W) ? 1.f : 0.f;
      float vx1 = ((unsigned)ix1 < (unsigned)W) ? 1.f : 0.f;
      int cy0 = iy0 < 0 ? 0 : (iy0 > H - 1 ? H - 1 : iy0);
      int cy1 = iy1 < 0 ? 0 : (iy1 > H - 1 ? H - 1 : iy1);
      int cx0 = ix0 < 0 ? 0 : (ix0 > W - 1 ? W - 1 : ix0);
      int cx1 = ix1 < 0 ? 0 : (ix1 > W - 1 ? W - 1 : ix1);
      o00[p] = cy0 * W + cx0; o01[p] = cy0 * W + cx1;
      o10[p] = cy1 * W + cx0; o11[p] = cy1 * W + cx1;
      w00[p] = wy0 * wx0 * vy0 * vx0;
      w01[p] = wy0 * wx1 * vy0 * vx1;
      w10[p] = wy1 * wx0 * vy1 * vx0;
      w11[p] = wy1 * wx1 * vy1 * vx1;
    }

    float* outn = out + (size_t)n * C * (2 * H) * (2 * W);
    for (int c = sg * 16; c < sg * 16 + 16; ++c) {
      const float* xc = xn + (size_t)c * HW;
      float s[4];
#pragma unroll
      for (int p = 0; p < 4; ++p) {
        s[p] = w00[p] * xc[o00[p]] + w01[p] * xc[o01[p]] +
               w10[p] * xc[o10[p]] + w11[p] * xc[o11[p]];
      }
      float* oc = outn + (size_t)c * (2 * H) * (2 * W);
      float2* r0 = (float2*)(oc + (size_t)(2 * y) * (2 * W) + 2 * xx);
      float2* r1 = (float2*)(oc + (size_t)(2 * y + 1) * (2 * W) + 2 * xx);
      *r0 = make_float2(s[0], s[1]);
      *r1 = make_float2(s[2], s[3]);
    }
  }
}

extern "C" void kernel_launch(void* const* d_in, const int* in_sizes, int n_in,
                              void* d_out, int out_size, void* d_ws, size_t ws_size,
                              hipStream_t stream) {
  const float* x = (const float*)d_in[0];
  const float* w = (const float*)d_in[1];
  const float* b = (const float*)d_in[2];
  float* out = (float*)d_out;

  const size_t xt_bytes = (size_t)NB * HW * C * sizeof(float);   // 32 MB
  const size_t wt_bytes = (size_t)9216 * sizeof(float);          // 36.9 KB
  dim3 block(256);

  if (d_ws != nullptr && ws_size >= xt_bytes + wt_bytes) {
    float* xt = (float*)d_ws;
    float* wt2 = (float*)((char*)d_ws + xt_bytes);
    prep_wt2<<<dim3(36), block, 0, stream>>>(w, wt2);
    transpose_nchw_nhwc<<<dim3(NB * (HW / TPX)), block, 0, stream>>>(x, xt);
    dcn_fused_t9<<<dim3(NB * H * NSEG), block, 0, stream>>>(xt, wt2, b, out);
  } else {
    dcn_fused<<<dim3(NB * H * NSEG), block, 0, stream>>>(x, w, b, out);
  }
}